// Round 9
// baseline (189.497 us; speedup 1.0000x reference)
//
#include <hip/hip_runtime.h>
#include <hip/hip_fp16.h>
#include <cmath>

// SVC_63737314673237 round 11: occupancy doubling via tile halving.
// R10 post-mortem: counted-vmcnt gave only +2% -> stall is NOT staging
// latency. Pipe accounting: DS 51%, VALU 33%, MFMA 30%, occupancy 8.6
// waves/CU -- TLP-starved, all pipes half-idle. R11 trades per-work DS
// efficiency (+33% frag reads) for residency: block 64sv x 64n (waves 2x2
// of 32x32), 8 chunks x 8 kb = 64 phases, LDS 48KB -> 32KB -> 4 blocks/CU
// (16 waves). Predicted DS-saturation wall ~75us.
// Carried verified pieces: split-f16 3-pass GEMM, (row>>1)&3 conflict-free
// hash, counted-vmcnt(4) top-barrier schedule, PV-MFMA epilogue, [90][N] T.

#define GAMMA 0.01f
constexpr int N  = 8192;
constexpr int D  = 256;
constexpr int S  = 5000;
constexpr int C  = 10;
constexpr int NV = 500;
constexpr int R  = 9;     // C-1
constexpr int SPAD = 5120; // 10 classes x 512 padded cols

constexpr int ROW_BLOCKS = (N + S) / 4;       // 3298 (13192 row-waves, 4/block)
constexpr int A_BLOCKS   = (16 * SPAD) / 256; // 320

typedef _Float16 f16x8 __attribute__((ext_vector_type(8)));
typedef _Float16 f16x4 __attribute__((ext_vector_type(4)));
typedef float    f32x4 __attribute__((ext_vector_type(4)));

__device__ __forceinline__ void gload16(const void* g, void* l) {
    __builtin_amdgcn_global_load_lds(
        (const __attribute__((address_space(1))) void*)g,
        (__attribute__((address_space(3))) void*)l, 16, 0, 0);
}

// ---------------- fused split + norms + a-split + svnp ----------------------
__global__ __launch_bounds__(256) void prep_kernel(const float* __restrict__ x,
                                                   const float* __restrict__ sv,
                                                   const float* __restrict__ a,
                                                   _Float16* __restrict__ xh,
                                                   _Float16* __restrict__ xl,
                                                   _Float16* __restrict__ sh,
                                                   _Float16* __restrict__ sl,
                                                   float* __restrict__ xn,
                                                   _Float16* __restrict__ ah,
                                                   _Float16* __restrict__ al,
                                                   float* __restrict__ svnp) {
    if (blockIdx.x >= ROW_BLOCKS) {
        int idx = (blockIdx.x - ROW_BLOCKS) * 256 + threadIdx.x;
        int r = idx / SPAD, col = idx - r * SPAD;
        int cls = col >> 9, j = col & 511;
        int s = cls * NV + ((j < NV) ? j : NV - 1);
        float av = (r < R && j < NV) ? a[(size_t)r * S + s] : 0.0f;
        _Float16 h = (_Float16)av;
        ah[idx] = h;
        al[idx] = (_Float16)((av - (float)h) * 4096.0f);
        return;
    }
    int gid  = blockIdx.x * blockDim.x + threadIdx.x;
    int wid  = gid >> 6;
    int lane = gid & 63;
    bool isx = wid < N;
    int  r   = isx ? wid : wid - N;
    const float* row = isx ? (x + (size_t)r * D) : (sv + (size_t)r * D);
    float4 v = reinterpret_cast<const float4*>(row)[lane];
    float s = v.x * v.x + v.y * v.y + v.z * v.z + v.w * v.w;
#pragma unroll
    for (int off = 32; off > 0; off >>= 1) s += __shfl_xor(s, off, 64);
    float vv[4] = {v.x, v.y, v.z, v.w};
    f16x4 h, l;
#pragma unroll
    for (int k = 0; k < 4; ++k) {
        _Float16 hi = (_Float16)vv[k];
        h[k] = hi;
        l[k] = (_Float16)((vv[k] - (float)hi) * 4096.0f);
    }
    size_t o = (size_t)r * D + lane * 4;
    *(f16x4*)((isx ? xh : sh) + o) = h;
    *(f16x4*)((isx ? xl : sl) + o) = l;
    if (lane == 0) {
        if (isx) {
            xn[r] = s;
        } else {
            int cls = r / NV, j = r - cls * NV;
            svnp[cls * 512 + j] = s;
            if (j == NV - 1)                      // fill pad cols 500..511
                for (int p = NV; p < 512; ++p) svnp[cls * 512 + p] = s;
        }
    }
}

// ---------------- swapped split-MFMA GEMM + exp + PV-MFMA reduce ------------
// grid: (128 n-tiles of 64, 10 classes). block 256 = 4 waves (wm,wn 2x2).
// wave tile: 32 sv x 32 n = 2x2 mfma tiles (16x16x32). 64 phases =
// 8 sv-chunks x 8 kb; gload_lds DMA double-buffer (32KB -> 4 blocks/CU).
// Phase: {issue stage(ph+1); vmcnt(4); s_barrier; ds_reads; setprio MFMAs;
// [chunk epilogue]; lgkmcnt(0); s_barrier} -- prefetch never drained to 0.
__global__ __launch_bounds__(256, 4) void svc_gemm(const _Float16* __restrict__ xh,
                                                   const _Float16* __restrict__ xl,
                                                   const _Float16* __restrict__ sh,
                                                   const _Float16* __restrict__ sl,
                                                   const _Float16* __restrict__ ahp,
                                                   const _Float16* __restrict__ alp,
                                                   const float* __restrict__ xnorm,
                                                   const float* __restrict__ svnp,
                                                   float* __restrict__ T) {
    __shared__ _Float16 SVs[2][2][64 * 32];   // 16KB: M-operand (sv rows)
    __shared__ _Float16 Xs[2][2][64 * 32];    // 16KB: N-operand (x rows)

    const int tid  = threadIdx.x;
    const int n0   = blockIdx.x * 64;
    const int cls  = blockIdx.y;
    const int w    = tid >> 6;
    const int lane = tid & 63;
    const int wm   = w >> 1;   // splits 64 m
    const int wn   = w & 1;    // splits 64 n
    const int lx   = lane & 15;
    const int quad = lane >> 4;

    float xnr[2];
#pragma unroll
    for (int nt = 0; nt < 2; ++nt)
        xnr[nt] = xnorm[n0 + wn * 32 + nt * 16 + lx];

    // fragment read offsets, inverse of staged K-slot perm f(row)=(row>>1)&3
    int svoff[2], xoff[2];
#pragma unroll
    for (int mt = 0; mt < 2; ++mt) {
        int row = wm * 32 + mt * 16 + lx;
        svoff[mt] = row * 32 + ((quad - (row >> 1)) & 3) * 8;
    }
#pragma unroll
    for (int nt = 0; nt < 2; ++nt) {
        int row = wn * 32 + nt * 16 + lx;
        xoff[nt] = row * 32 + ((quad - (row >> 1)) & 3) * 8;
    }

    const int arow = tid >> 2, ag = tid & 3;   // arow 0..63
    const int sg   = (ag + (arow >> 1)) & 3;
    const int segend = cls * NV + NV - 1;
    const int ldsw = w * 512;

    auto stage = [&](int ph, int buf) {
        const int ch = ph >> 3, kb = ph & 7;
        const size_t koff = (size_t)(kb * 32 + sg * 8);
        const size_t goX  = (size_t)(n0 + arow) * D + koff;
        gload16(xh + goX, &Xs[buf][0][ldsw]);
        gload16(xl + goX, &Xs[buf][1][ldsw]);
        int svr = cls * NV + ch * 64 + arow;
        if (svr > segend) svr = segend;
        const size_t go = (size_t)svr * D + koff;
        gload16(sh + go, &SVs[buf][0][ldsw]);
        gload16(sl + go, &SVs[buf][1][ldsw]);
    };

    f32x4 accM[2][2], accC[2][2];      // first-GEMM tiles [mt][nt]
#pragma unroll
    for (int mt = 0; mt < 2; ++mt)
#pragma unroll
        for (int nt = 0; nt < 2; ++nt) {
            accM[mt][nt] = (f32x4){0.f, 0.f, 0.f, 0.f};
            accC[mt][nt] = (f32x4){0.f, 0.f, 0.f, 0.f};
        }
    f32x4 accO[2], accOC[2];           // PV output tiles [nt] (r x n)
#pragma unroll
    for (int nt = 0; nt < 2; ++nt) {
        accO[nt]  = (f32x4){0.f, 0.f, 0.f, 0.f};
        accOC[nt] = (f32x4){0.f, 0.f, 0.f, 0.f};
    }

    stage(0, 0);

    for (int ph = 0; ph < 64; ++ph) {
        const int buf = ph & 1;
        // phase top: issue next stage, counted drain of stage(ph) only
        if (ph < 63) {
            stage(ph + 1, buf ^ 1);
            asm volatile("s_waitcnt vmcnt(4)" ::: "memory");
        } else {
            asm volatile("s_waitcnt vmcnt(0)" ::: "memory");
        }
        __builtin_amdgcn_s_barrier();      // all waves' stage(ph) visible
        asm volatile("" ::: "memory");

        f16x8 Am[2][2], Bx[2][2];
#pragma unroll
        for (int mt = 0; mt < 2; ++mt) {
            Am[0][mt] = *(const f16x8*)(&SVs[buf][0][svoff[mt]]);
            Am[1][mt] = *(const f16x8*)(&SVs[buf][1][svoff[mt]]);
        }
#pragma unroll
        for (int nt = 0; nt < 2; ++nt) {
            Bx[0][nt] = *(const f16x8*)(&Xs[buf][0][xoff[nt]]);
            Bx[1][nt] = *(const f16x8*)(&Xs[buf][1][xoff[nt]]);
        }
        __builtin_amdgcn_s_setprio(1);
#pragma unroll
        for (int mt = 0; mt < 2; ++mt)
#pragma unroll
            for (int nt = 0; nt < 2; ++nt) {
                accM[mt][nt] = __builtin_amdgcn_mfma_f32_16x16x32_f16(
                    Am[0][mt], Bx[0][nt], accM[mt][nt], 0, 0, 0);
                accC[mt][nt] = __builtin_amdgcn_mfma_f32_16x16x32_f16(
                    Am[0][mt], Bx[1][nt], accC[mt][nt], 0, 0, 0);
                accC[mt][nt] = __builtin_amdgcn_mfma_f32_16x16x32_f16(
                    Am[1][mt], Bx[0][nt], accC[mt][nt], 0, 0, 0);
            }
        __builtin_amdgcn_s_setprio(0);

        if ((ph & 7) == 7) {   // chunk done: exp + PV-MFMA reduce (no DS)
            const int ch = ph >> 3;
            const int mbase = cls * 512 + ch * 64 + wm * 32;
#pragma unroll
            for (int mt = 0; mt < 2; ++mt) {
                const size_t ao = (size_t)lx * SPAD + mbase + mt * 16 + quad * 4;
                f16x4 afh = *(const f16x4*)(ahp + ao);   // A-frag: a[r=lx, k]
                f16x4 afl = *(const f16x4*)(alp + ao);
                float4 sn4 = *(const float4*)(svnp + mbase + mt * 16 + quad * 4);
#pragma unroll
                for (int nt = 0; nt < 2; ++nt) {
                    f16x4 bh, bl;   // B-frag: kv[k = quad*4+reg, col = lx]
#pragma unroll
                    for (int reg = 0; reg < 4; ++reg) {
                        float dot = accM[mt][nt][reg]
                                  + accC[mt][nt][reg] * (1.0f / 4096.0f);
                        float e  = fmaf(2.0f * GAMMA, dot,
                                        -GAMMA * (xnr[nt] + sn4[reg]));
                        float kv = __expf(e);
                        _Float16 h = (_Float16)kv;
                        bh[reg] = h;
                        bl[reg] = (_Float16)((kv - (float)h) * 4096.0f);
                    }
                    accO[nt]  = __builtin_amdgcn_mfma_f32_16x16x16f16(
                        afh, bh, accO[nt], 0, 0, 0);
                    accOC[nt] = __builtin_amdgcn_mfma_f32_16x16x16f16(
                        afh, bl, accOC[nt], 0, 0, 0);
                    accOC[nt] = __builtin_amdgcn_mfma_f32_16x16x16f16(
                        afl, bh, accOC[nt], 0, 0, 0);
                    accM[mt][nt] = (f32x4){0.f, 0.f, 0.f, 0.f};
                    accC[mt][nt] = (f32x4){0.f, 0.f, 0.f, 0.f};
                }
            }
        }

        // phase bottom: ds_reads of buf done; barrier guards next DMA. NO vmcnt.
        asm volatile("s_waitcnt lgkmcnt(0)" ::: "memory");
        __builtin_amdgcn_s_barrier();
        asm volatile("" ::: "memory");
    }

    // cross-wm reduce via reused SVs space (8KB), then store T ([90][N]).
    float* scr = (float*)&SVs[0][0][0];
    if (wm == 0) {
#pragma unroll
        for (int nt = 0; nt < 2; ++nt)
#pragma unroll
            for (int reg = 0; reg < 4; ++reg) {
                int base = ((wn * 2 + nt) * 2) * 256 + (quad * 4 + reg) * 16 + lx;
                scr[base]       = accO[nt][reg];
                scr[base + 256] = accOC[nt][reg];
            }
    }
    __syncthreads();
    if (wm == 1) {
#pragma unroll
        for (int nt = 0; nt < 2; ++nt)
#pragma unroll
            for (int reg = 0; reg < 4; ++reg) {
                int r = quad * 4 + reg;
                if (r < R) {
                    int base = ((wn * 2 + nt) * 2) * 256 + r * 16 + lx;
                    float o  = accO[nt][reg]  + scr[base];
                    float oc = accOC[nt][reg] + scr[base + 256];
                    int n = n0 + wn * 32 + nt * 16 + lx;
                    T[(size_t)(r * 10 + cls) * N + n] = o + oc * (1.0f / 4096.0f);
                }
            }
    }
}

// ---------------- pairwise voting + argmax ----------------------------------
// T is [90][N]: every load below is a coalesced 1KB/wave read.
__global__ __launch_bounds__(256) void vote_kernel(const float* __restrict__ T,
                                                   const float* __restrict__ b,
                                                   int* __restrict__ out) {
    int n = blockIdx.x * blockDim.x + threadIdx.x;
    if (n >= N) return;
    float tv[90];
#pragma unroll
    for (int i = 0; i < 90; ++i) tv[i] = T[(size_t)i * N + n];
    int counts[C];
#pragma unroll
    for (int k = 0; k < C; ++k) counts[k] = 0;
    int p = 0;
#pragma unroll
    for (int i = 0; i < C; ++i) {
#pragma unroll
        for (int j = i + 1; j < C; ++j) {
            float c = tv[i * 10 + j] + tv[(j - 1) * 10 + i] + b[p];
            if (c > 0.f) counts[i]++; else counts[j]++;
            ++p;
        }
    }
    int best = 0;
#pragma unroll
    for (int k = 1; k < C; ++k)
        if (counts[k] > counts[best]) best = k;
    out[n]     = best;
    out[N + n] = best;
}

extern "C" void kernel_launch(void* const* d_in, const int* in_sizes, int n_in,
                              void* d_out, int out_size, void* d_ws, size_t ws_size,
                              hipStream_t stream) {
    const float* x  = (const float*)d_in[0];   // [8192,256]
    const float* sv = (const float*)d_in[1];   // [5000,256]
    const float* a  = (const float*)d_in[2];   // [9,5000]
    const float* b  = (const float*)d_in[3];   // [45]
    int* out = (int*)d_out;

    char* wp = (char*)d_ws;
    _Float16* xh = (_Float16*)wp;  wp += (size_t)N * D * 2;
    _Float16* xl = (_Float16*)wp;  wp += (size_t)N * D * 2;
    _Float16* sh = (_Float16*)wp;  wp += (size_t)S * D * 2;
    _Float16* sl = (_Float16*)wp;  wp += (size_t)S * D * 2;
    float* xnorm  = (float*)wp;    wp += (size_t)N * 4;
    _Float16* ahp = (_Float16*)wp; wp += (size_t)16 * SPAD * 2;
    _Float16* alp = (_Float16*)wp; wp += (size_t)16 * SPAD * 2;
    float* svnp   = (float*)wp;    wp += (size_t)SPAD * 4;
    float* T      = (float*)wp;    // [90][N]

    {   // fused split + norms + a-split + svnp (one launch)
        prep_kernel<<<ROW_BLOCKS + A_BLOCKS, 256, 0, stream>>>(
            x, sv, a, xh, xl, sh, sl, xnorm, ahp, alp, svnp);
    }
    {   // swapped GEMM + PV-MFMA reduce
        dim3 grid(N / 64, C);
        svc_gemm<<<grid, 256, 0, stream>>>(xh, xl, sh, sl, ahp, alp,
                                           xnorm, svnp, T);
    }
    {   // voting
        vote_kernel<<<N / 256, 256, 0, stream>>>(T, b, out);
    }
}